// Round 5
// baseline (14512.778 us; speedup 1.0000x reference)
//
#include <hip/hip_runtime.h>
#include <hip/hip_bf16.h>
#include <stdint.h>

// ---------------- problem constants ----------------
#define B_   128
#define T_   512
#define H_   1024
#define NG   6144             // 2 dirs * 3 gates * H_
#define ND   3072             // per-dir gate width
#define LNEPS 1e-6f

typedef __attribute__((ext_vector_type(8))) short  short8_t;   // bf16x8 MFMA frag
typedef __attribute__((ext_vector_type(4))) float  f32x4_t;    // MFMA acc

typedef const __attribute__((address_space(1))) uint8_t* gptr_t;
typedef       __attribute__((address_space(3))) uint8_t* lptr_t;

__device__ __forceinline__ f32x4_t mfma16(short8_t a, short8_t b, f32x4_t c){
  return __builtin_amdgcn_mfma_f32_16x16x32_bf16(a, b, c, 0, 0, 0);
}

__device__ __forceinline__ unsigned short f2bf(float f){   // RNE, finite inputs
  unsigned u = __builtin_bit_cast(unsigned, f);
  return (unsigned short)((u + 0x7FFFu + ((u >> 16) & 1u)) >> 16);
}
__device__ __forceinline__ float bf2f(unsigned short s){
  unsigned u = ((unsigned)s) << 16;
  return __builtin_bit_cast(float, u);
}
__device__ __forceinline__ float ldx(float v){ return v; }
__device__ __forceinline__ float ldx(unsigned short v){ return bf2f(v); }

// Stage ROWS rows x 128 bytes (64 bf16) from global row-major (stride sb bytes)
// into linear LDS [ROWS][128] via global_load_lds(16B). The read-side XOR
// swizzle (G4: byte ^= (row&7)<<4) is pre-applied to the SOURCE column so the
// LDS destination stays linear (m173/m201 pattern).
template<int ROWS>
__device__ __forceinline__ void stage_rows(const uint8_t* g, size_t sb, uint8_t* lds, int tid){
  int w    = tid >> 6;
  int colb = ((tid & 7) << 4) ^ (((tid >> 3) & 7) << 4);
  int rin  = tid >> 3;                       // 0..31
  #pragma unroll
  for (int q = 0; q < ROWS; q += 32){
    const uint8_t* src = g + (size_t)(q + rin) * sb + colb;
    uint8_t*       dst = lds + (size_t)(q + w * 8) * 128;
    __builtin_amdgcn_global_load_lds((gptr_t)src, (lptr_t)dst, 16, 0, 0);
  }
}

// read one 16x32 bf16 fragment row-slice: lane reads 8 bf16 at (row, kt*32 + (lane>>4)*8)
__device__ __forceinline__ short8_t read_frag(const uint8_t* lds, int row, int kt, int lane){
  int boff = ((kt << 6) + ((lane >> 4) << 4)) ^ ((row & 7) << 4);
  return *(const short8_t*)(lds + (size_t)row * 128 + boff);
}

// ---------------- m97-style bf16 GEMM: C[M,N] = A[M,K] * BT[N,K]^T (+bias) ----------------
// Requires M%1024==0 (group-of-8 m-tiles), N%128==0, K%64==0.
template<typename OUT_T, bool BIAS>
__global__ __launch_bounds__(256, 2)
void ce_gemm_bt(const unsigned short* __restrict__ A, const unsigned short* __restrict__ BT,
                OUT_T* __restrict__ C, const float* __restrict__ bias,
                int M, int N, int K){
  __shared__ __align__(16) uint8_t Al[128 * 128];
  __shared__ __align__(16) uint8_t Bl[128 * 128];
  int tid = threadIdx.x, lane = tid & 63, wid = tid >> 6;
  int nt = N >> 7;
  int per = nt * 8;
  int gid = blockIdx.x / per, lid = blockIdx.x % per;
  int bm = gid * 8 + (lid & 7);
  int bn = lid >> 3;
  const uint8_t* Ab = (const uint8_t*)A  + (size_t)bm * 128 * K * 2;
  const uint8_t* Bb = (const uint8_t*)BT + (size_t)bn * 128 * K * 2;
  int wm = wid >> 1, wn = wid & 1;
  f32x4_t acc[4][4] = {};
  int nkc = K >> 6;
  for (int kc = 0; kc < nkc; ++kc){
    __syncthreads();                               // protect LDS from previous iter readers
    stage_rows<128>(Ab + kc * 128, (size_t)K * 2, Al, tid);
    stage_rows<128>(Bb + kc * 128, (size_t)K * 2, Bl, tid);
    asm volatile("s_waitcnt vmcnt(0)" ::: "memory");
    __syncthreads();
    #pragma unroll
    for (int kt = 0; kt < 2; ++kt){
      short8_t af[4], bf[4];
      #pragma unroll
      for (int i = 0; i < 4; i++) af[i] = read_frag(Al, wm * 64 + i * 16 + (lane & 15), kt, lane);
      #pragma unroll
      for (int j = 0; j < 4; j++) bf[j] = read_frag(Bl, wn * 64 + j * 16 + (lane & 15), kt, lane);
      #pragma unroll
      for (int i = 0; i < 4; i++)
        #pragma unroll
        for (int j = 0; j < 4; j++)
          acc[i][j] = mfma16(af[i], bf[j], acc[i][j]);
    }
  }
  int r0 = (lane >> 4) << 2, cl = lane & 15;
  #pragma unroll
  for (int i = 0; i < 4; i++){
    int row = bm * 128 + wm * 64 + i * 16 + r0;
    #pragma unroll
    for (int j = 0; j < 4; j++){
      int col = bn * 128 + wn * 64 + j * 16 + cl;
      float bv = BIAS ? bias[col] : 0.0f;
      #pragma unroll
      for (int r = 0; r < 4; r++){
        float v = acc[i][j][r] + bv;
        size_t o = (size_t)(row + r) * N + col;
        if constexpr (sizeof(OUT_T) == 2) C[o] = f2bf(v); else C[o] = v;
      }
    }
  }
}

// ---------------- GRU scan step: both dirs, one kernel ----------------
// grid = 64: blocks 0..31 forward (32 h-cols each), 32..63 backward.
// xiF/xiB: per-step per-dir [128 rows][3072] gate slabs (r|z|n per 32-col group).
template<typename XIT>
__global__ __launch_bounds__(256, 1)
void ce_scan(const XIT* __restrict__ xiF, const XIT* __restrict__ xiB,
             const unsigned short* __restrict__ WhT,
             const float* __restrict__ bhnF, const float* __restrict__ bhnB,
             float* __restrict__ hF, unsigned short* __restrict__ hB, int pin){
  __shared__ __align__(16) uint8_t Al[2][128 * 128];   // h tile  [128][64 bf16]
  __shared__ __align__(16) uint8_t Bl[2][96 * 128];    // Wh tile [96][64 bf16]
  int tid = threadIdx.x, lane = tid & 63, w = tid >> 6;
  int dir = blockIdx.x >> 5, j = blockIdx.x & 31;
  int pout = pin ^ 1;
  const uint8_t*  hA    = (const uint8_t*)(hB + (size_t)(pin  * 2 + dir) * (B_ * H_));
  const float*    hOld  = hF + (size_t)(pin  * 2 + dir) * (B_ * H_);
  float*          hNewF = hF + (size_t)(pout * 2 + dir) * (B_ * H_);
  unsigned short* hNewB = hB + (size_t)(pout * 2 + dir) * (B_ * H_);
  const uint8_t*  Bb = (const uint8_t*)(WhT + ((size_t)dir * ND + (size_t)j * 96) * H_);
  const float*    bhn = dir ? bhnB : bhnF;
  const XIT*      xi  = dir ? xiB  : xiF;

  f32x4_t acc[2][6] = {};
  stage_rows<128>(hA, H_ * 2, Al[0], tid);     // 4 loads/wave
  stage_rows<96 >(Bb, H_ * 2, Bl[0], tid);     // 3 loads/wave
  for (int kc = 0; kc < 16; ++kc){
    int cur = kc & 1;
    if (kc < 15){
      stage_rows<128>(hA + (size_t)(kc + 1) * 128, H_ * 2, Al[cur ^ 1], tid);
      stage_rows<96 >(Bb + (size_t)(kc + 1) * 128, H_ * 2, Bl[cur ^ 1], tid);
      asm volatile("s_waitcnt vmcnt(7)" ::: "memory");   // wait current tile, keep next in flight
    } else {
      asm volatile("s_waitcnt vmcnt(0)" ::: "memory");
    }
    __builtin_amdgcn_s_barrier();
    __builtin_amdgcn_sched_barrier(0);
    #pragma unroll
    for (int kt = 0; kt < 2; ++kt){
      short8_t af[2], bf6[6];
      #pragma unroll
      for (int mt = 0; mt < 2; mt++) af[mt]  = read_frag(Al[cur], w * 32 + mt * 16 + (lane & 15), kt, lane);
      #pragma unroll
      for (int nt = 0; nt < 6; nt++) bf6[nt] = read_frag(Bl[cur], nt * 16 + (lane & 15), kt, lane);
      #pragma unroll
      for (int mt = 0; mt < 2; mt++)
        #pragma unroll
        for (int nt = 0; nt < 6; nt++)
          acc[mt][nt] = mfma16(af[mt], bf6[nt], acc[mt][nt]);
    }
    __builtin_amdgcn_s_barrier();
    __builtin_amdgcn_sched_barrier(0);
  }
  // gates (flax GRUCell): r=sig(xr+hWr) z=sig(xz+hWz) n=tanh(xn + r*(hWn+bhn)) h'=(1-z)n+zh
  int cl = lane & 15, r0 = (lane >> 4) << 2;
  #pragma unroll
  for (int mt = 0; mt < 2; mt++){
    #pragma unroll
    for (int ct = 0; ct < 2; ct++){
      #pragma unroll
      for (int r = 0; r < 4; r++){
        int row = w * 32 + mt * 16 + r0 + r;
        int hcl = ct * 16 + cl;
        int hcg = j * 32 + hcl;
        size_t xb = (size_t)row * ND + (size_t)j * 96;
        float xr = ldx(xi[xb + hcl]);
        float xz = ldx(xi[xb + 32 + hcl]);
        float xn = ldx(xi[xb + 64 + hcl]);
        float rp = acc[mt][ct][r], zp = acc[mt][ct + 2][r], np = acc[mt][ct + 4][r];
        float rg = 1.0f / (1.0f + expf(-(xr + rp)));
        float zg = 1.0f / (1.0f + expf(-(xz + zp)));
        float ng = tanhf(xn + rg * (np + bhn[hcg]));
        float ho = hOld[(size_t)row * H_ + hcg];
        float hv = (1.0f - zg) * ng + zg * ho;
        hNewF[(size_t)row * H_ + hcg] = hv;
        hNewB[(size_t)row * H_ + hcg] = f2bf(hv);
      }
    }
  }
}

// ---------------- prep kernels ----------------
// feat chunk in T-major layout: dst[(ell*128 + b)*1024 + col], t = tbase + ell
__global__ __launch_bounds__(256)
void ce_featc(const float* __restrict__ z, const float* __restrict__ mu, const float* __restrict__ lv,
              unsigned short* __restrict__ dst, int tbase){
  size_t e = ((size_t)blockIdx.x * 256 + threadIdx.x) * 4;
  int ell = (int)(e >> 17);
  int b   = (int)((e >> 10) & 127);
  int col = (int)(e & 1023);
  int t = tbase + ell;
  const float* s;
  if      (col < 512) s = z  + ((size_t)b * T_ + t) * 512 + col;
  else if (col < 768) s = mu + ((size_t)b * T_ + t) * 256 + (col - 512);
  else                s = lv + ((size_t)b * T_ + t) * 256 + (col - 768);
  float4 v = *(const float4*)s;
  ushort4 o; o.x = f2bf(v.x); o.y = f2bf(v.y); o.z = f2bf(v.z); o.w = f2bf(v.w);
  *(ushort4*)(dst + e) = o;
}

__global__ __launch_bounds__(256)
void ce_cast4(const float* __restrict__ s, unsigned short* __restrict__ d, int n4){
  int i = blockIdx.x * 256 + threadIdx.x;
  if (i >= n4) return;
  float4 v = ((const float4*)s)[i];
  ushort4 o; o.x = f2bf(v.x); o.y = f2bf(v.y); o.z = f2bf(v.z); o.w = f2bf(v.w);
  ((ushort4*)d)[i] = o;
}

// permuted transpose: dst[j*96+g*32+c][k] = src[k][g*1024+j*32+c], src [1024 x 3072] f32
__global__ __launch_bounds__(256)
void ce_tperm(const float* __restrict__ src, unsigned short* __restrict__ dst){
  __shared__ float tl[32][33];
  int b = blockIdx.x;
  int kt = b & 31, gj = b >> 5;
  int g = gj % 3, j = gj / 3;
  int c0 = g * H_ + j * 32, k0 = kt * 32, m0 = j * 96 + g * 32;
  int tx = threadIdx.x & 31, ty = threadIdx.x >> 5;
  #pragma unroll
  for (int i = 0; i < 32; i += 8) tl[ty + i][tx] = src[(size_t)(k0 + ty + i) * 3072 + c0 + tx];
  __syncthreads();
  #pragma unroll
  for (int i = 0; i < 32; i += 8) dst[(size_t)(m0 + ty + i) * H_ + k0 + tx] = f2bf(tl[tx][ty + i]);
}

// b_comb[m] = bi[col(m)] + sum_k proj_b[k]*Wi[k][col(m)]
__global__ __launch_bounds__(256)
void ce_bcomb(const float* __restrict__ pb, const float* __restrict__ WiF, const float* __restrict__ biF,
              const float* __restrict__ WiB, const float* __restrict__ biB, float* __restrict__ bc){
  int m = blockIdx.x * 256 + threadIdx.x;
  int dir = m / ND, mm = m % ND;
  int j = mm / 96, gc = mm % 96, g = gc >> 5, c = gc & 31;
  int col = g * H_ + j * 32 + c;
  const float* Wi = dir ? WiB : WiF;
  const float* bi = dir ? biB : biF;
  float s = bi[col];
  for (int k = 0; k < H_; k++) s += pb[k] * Wi[(size_t)k * 3072 + col];
  bc[m] = s;
}

// ---------------- tail kernels ----------------
__global__ __launch_bounds__(256)
void ce_ln(const float* __restrict__ hF, const float* __restrict__ gam, const float* __restrict__ bet,
           float* __restrict__ out){
  int row = blockIdx.x, tid = threadIdx.x;
  const float* hf = hF + (size_t)row * H_;                      // dir0, par0
  const float* hb = hF + (size_t)(B_ * H_) + (size_t)row * H_;  // dir1, par0
  float v[8]; float s1 = 0.f, s2 = 0.f;
  #pragma unroll
  for (int i = 0; i < 8; i++){
    int c = tid + i * 256;
    float x = (i < 4) ? hf[c] : hb[c - H_];
    v[i] = x; s1 += x; s2 += x * x;
  }
  #pragma unroll
  for (int o = 32; o > 0; o >>= 1){ s1 += __shfl_down(s1, o); s2 += __shfl_down(s2, o); }
  __shared__ float rs[8];
  __shared__ float mv[2];
  int w = tid >> 6, lane = tid & 63;
  if (lane == 0){ rs[w] = s1; rs[4 + w] = s2; }
  __syncthreads();
  if (tid == 0){
    float a = rs[0] + rs[1] + rs[2] + rs[3];
    float q = rs[4] + rs[5] + rs[6] + rs[7];
    float mean = a / 2048.0f;
    float var = q / 2048.0f - mean * mean;
    mv[0] = mean; mv[1] = rsqrtf(var + LNEPS);
  }
  __syncthreads();
  float mean = mv[0], rstd = mv[1];
  #pragma unroll
  for (int i = 0; i < 8; i++){
    int c = tid + i * 256;
    out[(size_t)row * 2048 + c] = (v[i] - mean) * rstd * gam[c] + bet[c];
  }
}

template<bool RELU>
__global__ __launch_bounds__(256)
void ce_fc(const float* __restrict__ A, const float* __restrict__ W, const float* __restrict__ bias,
           float* __restrict__ out, int K, int N){
  __shared__ float Al[128][65];
  int tid = threadIdx.x;
  int colb = blockIdx.x * 32;
  int col = tid & 31, rg = tid >> 5;
  float acc[16] = {};
  for (int kc = 0; kc < (K >> 6); ++kc){
    __syncthreads();
    for (int idx = tid; idx < 128 * 64; idx += 256){
      int r = idx >> 6, c = idx & 63;
      Al[r][c] = A[(size_t)r * K + kc * 64 + c];
    }
    __syncthreads();
    #pragma unroll 8
    for (int kk = 0; kk < 64; ++kk){
      float wv = W[(size_t)(kc * 64 + kk) * N + colb + col];
      #pragma unroll
      for (int i = 0; i < 16; i++) acc[i] += Al[rg * 16 + i][kk] * wv;
    }
  }
  #pragma unroll
  for (int i = 0; i < 16; i++){
    float v = acc[i] + bias[colb + col];
    if (RELU) v = fmaxf(v, 0.0f);
    out[(size_t)(rg * 16 + i) * N + colb + col] = v;
  }
}

__global__ void ce_mask(float* p){ p[threadIdx.x] = 1.0f; }

// ---------------- templated pipeline over xi element type ----------------
template<typename XIT>
static void run_pipeline(int CT,
                         const float* z, const float* mu, const float* lv,
                         unsigned short* featC0, unsigned short* featC1,  // [2 parity][CT*128*1024]
                         XIT* xiC0, XIT* xiC1,                            // [2 parity][CT*128*ND]
                         const unsigned short* WcT, const float* bc,
                         const unsigned short* WhT,
                         const float* bhnF, const float* bhnB,
                         float* hF, unsigned short* hB, hipStream_t stream){
  size_t featCsz = (size_t)CT * 128 * 1024;
  size_t xiCsz   = (size_t)CT * 128 * ND;
  int nchunks = T_ / CT;
  int fgrid = CT * 128;                         // 256 thr * 4 elems = 1024 per block
  int ggrid = (CT * 128 / 128) * (ND / 128);
  for (int c = 0; c < nchunks; ++c){
    int p = c & 1;
    unsigned short* fF = featC0 + (size_t)p * featCsz;
    unsigned short* fB = featC1 + (size_t)p * featCsz;
    XIT* xF = xiC0 + (size_t)p * xiCsz;
    XIT* xB = xiC1 + (size_t)p * xiCsz;
    ce_featc<<<fgrid, 256, 0, stream>>>(z, mu, lv, fF, c * CT);
    ce_featc<<<fgrid, 256, 0, stream>>>(z, mu, lv, fB, T_ - (c + 1) * CT);
    ce_gemm_bt<XIT, true><<<ggrid, 256, 0, stream>>>(fF, WcT,                    xF, bc,      CT * 128, ND, H_);
    ce_gemm_bt<XIT, true><<<ggrid, 256, 0, stream>>>(fB, WcT + (size_t)ND * H_,  xB, bc + ND, CT * 128, ND, H_);
    for (int tt = 0; tt < CT; ++tt){
      int s = c * CT + tt;
      const XIT* xiFs = xF + (size_t)tt * 128 * ND;
      const XIT* xiBs = xB + (size_t)(CT - 1 - tt) * 128 * ND;
      ce_scan<XIT><<<64, 256, 0, stream>>>(xiFs, xiBs, WhT, bhnF, bhnB, hF, hB, s & 1);
    }
  }
}

// ---------------- host ----------------
extern "C" void kernel_launch(void* const* d_in, const int* in_sizes, int n_in,
                              void* d_out, int out_size, void* d_ws, size_t ws_size,
                              hipStream_t stream){
  const float* z    = (const float*)d_in[0];
  const float* mu   = (const float*)d_in[1];
  const float* lv   = (const float*)d_in[2];
  const float* pW   = (const float*)d_in[3];
  const float* pb   = (const float*)d_in[4];
  const float* WiF  = (const float*)d_in[5];
  const float* WhF  = (const float*)d_in[6];
  const float* biF  = (const float*)d_in[7];
  const float* bhnF = (const float*)d_in[8];
  const float* WiB  = (const float*)d_in[9];
  const float* WhB  = (const float*)d_in[10];
  const float* biB  = (const float*)d_in[11];
  const float* bhnB = (const float*)d_in[12];
  const float* lng  = (const float*)d_in[13];
  const float* lnb  = (const float*)d_in[14];
  const float* f1W  = (const float*)d_in[15];
  const float* f1b  = (const float*)d_in[16];
  const float* f2W  = (const float*)d_in[17];
  const float* f2b  = (const float*)d_in[18];

  // ---- workspace plan (all writes provably within ws_size) ----
  auto al = [](size_t x){ return (x + 255) & ~(size_t)255; };
  size_t fixed = al((size_t)NG * H_ * 2)      // WiT
               + al((size_t)H_ * H_ * 2)      // PWb
               + al((size_t)NG * H_ * 2)      // WcT
               + al((size_t)NG * 4)           // bc
               + al((size_t)2 * ND * H_ * 2)  // WhT
               + al((size_t)4 * B_ * H_ * 4)  // hF
               + al((size_t)4 * B_ * H_ * 2)  // hB
               + al((size_t)B_ * 2048 * 4)    // hn
               + al((size_t)B_ * 1024 * 4);   // f1o
  auto need = [&](int CT, size_t esz){
    return fixed + 4 * al((size_t)CT * 128 * 1024 * 2)      // feat chunks (2 dir x 2 par)
                 + 4 * al((size_t)CT * 128 * ND * esz);     // xi chunks
  };
  int CT; size_t esz;
  if      (need(32, 4) <= ws_size){ CT = 32; esz = 4; }     // ~280 MB
  else if (need(32, 2) <= ws_size){ CT = 32; esz = 2; }     // ~180 MB
  else if (need(8,  2) <= ws_size){ CT = 8;  esz = 2; }     // ~76 MB
  else return;  // ws too small for any plan: launch nothing -> clean absmax fail, not a crash

  uint8_t* ws = (uint8_t*)d_ws;
  size_t off = 0;
  auto alloc = [&](size_t bytes){ void* q = ws + off; off += al(bytes); return q; };
  unsigned short* WiT  = (unsigned short*)alloc((size_t)NG * H_ * 2);
  unsigned short* PWb  = (unsigned short*)alloc((size_t)H_ * H_ * 2);
  unsigned short* WcT  = (unsigned short*)alloc((size_t)NG * H_ * 2);
  float*          bc   = (float*)alloc((size_t)NG * 4);
  unsigned short* WhT  = (unsigned short*)alloc((size_t)2 * ND * H_ * 2);
  float*          hF   = (float*)alloc((size_t)4 * B_ * H_ * 4);   // [par][dir][B][H]
  unsigned short* hB   = (unsigned short*)alloc((size_t)4 * B_ * H_ * 2);
  float*          hn   = (float*)alloc((size_t)B_ * 2048 * 4);
  float*          f1o  = (float*)alloc((size_t)B_ * 1024 * 4);
  unsigned short* featC0 = (unsigned short*)alloc(2 * al((size_t)CT * 128 * 1024 * 2));
  unsigned short* featC1 = (unsigned short*)alloc(2 * al((size_t)CT * 128 * 1024 * 2));
  void*           xiC0   = alloc(2 * al((size_t)CT * 128 * ND * esz));
  void*           xiC1   = alloc(2 * al((size_t)CT * 128 * ND * esz));

  hipMemsetAsync(hF, 0, (size_t)2 * B_ * H_ * 4, stream);   // par0, both dirs
  hipMemsetAsync(hB, 0, (size_t)2 * B_ * H_ * 2, stream);

  // weight prep
  ce_cast4<<<(H_ * H_ / 4 + 255) / 256, 256, 0, stream>>>(pW, PWb, H_ * H_ / 4);
  ce_tperm<<<3072, 256, 0, stream>>>(WiF, WiT);
  ce_tperm<<<3072, 256, 0, stream>>>(WiB, WiT + (size_t)ND * H_);
  ce_tperm<<<3072, 256, 0, stream>>>(WhF, WhT);
  ce_tperm<<<3072, 256, 0, stream>>>(WhB, WhT + (size_t)ND * H_);
  ce_bcomb<<<NG / 256, 256, 0, stream>>>(pb, WiF, biF, WiB, biB, bc);

  // W_combT[m][d] = sum_h WiT[m][h] * projW[d][h]   (M=6144, N=1024, K=1024)
  ce_gemm_bt<unsigned short, false><<<(NG / 128) * (H_ / 128), 256, 0, stream>>>(
      WiT, PWb, WcT, nullptr, NG, H_, H_);

  if (esz == 4)
    run_pipeline<float>(CT, z, mu, lv, featC0, featC1, (float*)xiC0, (float*)xiC1,
                        WcT, bc, WhT, bhnF, bhnB, hF, hB, stream);
  else
    run_pipeline<unsigned short>(CT, z, mu, lv, featC0, featC1,
                                 (unsigned short*)xiC0, (unsigned short*)xiC1,
                                 WcT, bc, WhT, bhnF, bhnB, hF, hB, stream);

  ce_ln<<<B_, 256, 0, stream>>>(hF, lng, lnb, hn);
  ce_fc<true ><<<1024 / 32, 256, 0, stream>>>(hn,  f1W, f1b, f1o, 2048, 1024);
  ce_fc<false><<<2048 / 32, 256, 0, stream>>>(f1o, f2W, f2b, (float*)d_out, 1024, 2048);
  if (out_size >= B_ * 2048 + B_ * 2)
    ce_mask<<<1, 256, 0, stream>>>((float*)d_out + B_ * 2048);
}